// Round 8
// baseline (106.782 us; speedup 1.0000x reference)
//
#include <hip/hip_runtime.h>
#include <hip/hip_bf16.h>

#define D_MODEL 64
#define D_STATE 16
#define IMG     32
#define HW      (IMG*IMG)      // 1024
#define V       9
#define B       4
#define GROUPS  4
#define CPG     (D_MODEL/GROUPS) // 16

typedef float f32x4 __attribute__((ext_vector_type(4)));

// Streaming store: system-scope (sc0 sc1) + non-temporal (nt) -> intent:
// no L2/MALL allocation, don't evict the resident s_prev read stream.
__device__ __forceinline__ void stream_store4(float* p, f32x4 v) {
    asm volatile("global_store_dwordx4 %0, %1, off sc0 sc1 nt"
                 :: "v"(p), "v"(v) : "memory");
}

// ---------------- Kernel 1: GroupNorm ----------------
__global__ __launch_bounds__(256) void gn_kernel(
    const float* __restrict__ u, const float* __restrict__ gamma,
    const float* __restrict__ beta, float* __restrict__ un)
{
    const int b = blockIdx.x / GROUPS;
    const int g = blockIdx.x % GROUPS;
    const float* base = u + ((size_t)b*D_MODEL + g*CPG) * HW;
    const int NE = CPG * HW; // 16384

    float s = 0.f, s2 = 0.f;
    for (int i = threadIdx.x; i < NE; i += 256) {
        float v = base[i];
        s += v; s2 += v*v;
    }
    for (int off = 32; off; off >>= 1) {
        s  += __shfl_down(s,  off);
        s2 += __shfl_down(s2, off);
    }
    __shared__ float red0[4], red1[4];
    const int wave = threadIdx.x >> 6;
    if ((threadIdx.x & 63) == 0) { red0[wave] = s; red1[wave] = s2; }
    __syncthreads();
    if (threadIdx.x == 0) {
        float a = 0.f, c = 0.f;
        for (int i = 0; i < 4; i++) { a += red0[i]; c += red1[i]; }
        red0[0] = a; red1[0] = c;
    }
    __syncthreads();
    const float mean = red0[0] * (1.f/16384.f);
    const float var  = red1[0] * (1.f/16384.f) - mean*mean;
    const float rstd = rsqrtf(var + 1e-5f);

    for (int i = threadIdx.x; i < NE; i += 256) {
        int c = i >> 10;
        int d = g*CPG + c;
        float v = (base[i] - mean) * rstd;
        un[((size_t)b*D_MODEL + d)*HW + (i & (HW-1))] = v*gamma[d] + beta[d];
    }
}

// ---------------- Kernel 2: circular 3x3 convs, LDS-staged, 4 co / block ----------------
__global__ __launch_bounds__(256) void conv_kernel(
    const float* __restrict__ un,
    const float* __restrict__ w_delta, const float* __restrict__ b_delta,
    const float* __restrict__ w_B, const float* __restrict__ w_C,
    const float* __restrict__ dt_sp,
    float* __restrict__ delta, float* __restrict__ Bv, float* __restrict__ Cv)
{
    const int bx    = blockIdx.x;
    const int strip = bx & 3;
    const int cog   = (bx >> 2) % 24;
    const int b     = bx / 96;
    const int co0   = cog * 4;
    const int row0  = strip * 8;

    __shared__ float xs[16][10][32];
    __shared__ float wl[4][D_MODEL*9];

    for (int i = threadIdx.x; i < 4*D_MODEL*9; i += 256) {
        const int cl = i / (D_MODEL*9);
        const int rest = i % (D_MODEL*9);
        const int co = co0 + cl;
        const float* w = (co < 64) ? (w_delta + (size_t)co*(D_MODEL*9))
                       : (co < 80) ? (w_B + (size_t)(co-64)*(D_MODEL*9))
                                   : (w_C + (size_t)(co-80)*(D_MODEL*9));
        wl[cl][rest] = w[rest];
    }

    const int ly = threadIdx.x >> 5;
    const int ox = threadIdx.x & 31;
    const int oy = row0 + ly;

    const float* x = un + (size_t)b*D_MODEL*HW;
    float a0 = 0.f, a1 = 0.f, a2 = 0.f, a3 = 0.f;

    for (int c = 0; c < 4; c++) {
        __syncthreads();
        for (int i = threadIdx.x; i < 16*10*32; i += 256) {
            const int ci = i / 320;
            const int rr = (i % 320) >> 5;
            const int xx = i & 31;
            const int gy = (row0 - 1 + rr) & 31;
            xs[ci][rr][xx] = x[(size_t)(c*16 + ci)*HW + (gy << 5) + xx];
        }
        __syncthreads();

        #pragma unroll
        for (int ci = 0; ci < 16; ci++) {
            float v[3][3];
            #pragma unroll
            for (int dy = 0; dy < 3; dy++)
                #pragma unroll
                for (int dx = 0; dx < 3; dx++)
                    v[dy][dx] = xs[ci][ly + dy][(ox + dx + 31) & 31];
            const int cig = c*16 + ci;
            const float* w0 = &wl[0][cig*9];
            const float* w1 = &wl[1][cig*9];
            const float* w2 = &wl[2][cig*9];
            const float* w3 = &wl[3][cig*9];
            #pragma unroll
            for (int t = 0; t < 9; t++) {
                const float xv = v[t/3][t%3];
                a0 = fmaf(xv, w0[t], a0);
                a1 = fmaf(xv, w1[t], a1);
                a2 = fmaf(xv, w2[t], a2);
                a3 = fmaf(xv, w3[t], a3);
            }
        }
    }

    const int p = (oy << 5) + ox;
    const float dtsp = dt_sp[0];
    float accs[4] = {a0, a1, a2, a3};
    #pragma unroll
    for (int cl = 0; cl < 4; cl++) {
        const int co = co0 + cl;
        float acc = accs[cl];
        if (co < 64) {
            acc += b_delta[co] + dtsp;
            float sp = (acc > 15.f) ? acc : log1pf(__expf(acc));
            sp = fminf(fmaxf(sp, 1e-4f), 5.f);
            delta[((size_t)b*D_MODEL + co)*HW + p] = sp;
        } else if (co < 80) {
            Bv[((size_t)b*D_STATE + (co-64))*HW + p] = acc;
        } else {
            Cv[((size_t)b*D_STATE + (co-80))*HW + p] = acc;
        }
    }
}

// ---------------- Kernel 3: main fused state update ----------------
// grid = B*V*D_MODEL (2304) blocks x 256 threads.
// Circular shift via row re-addressing + __shfl x-rotation (validated r4-r7).
// s_new stores use sc0|sc1|nt streaming stores (no L2/MALL allocate intent).
// A = -exp(log_A) folded in (aneg kernel removed).
template<int MODE>  // 0: rxo==0, 1: rxo==1 (src[x+1]), 2: rxo==31 (src[x-1])
__device__ __forceinline__ void main_body(
    const float* __restrict__ sp_base, float* __restrict__ sn_base,
    const float* __restrict__ Bv_b, const float* __restrict__ Cv_b,
    const f32x4 dl, const f32x4 du, const float* an_,
    f32x4& y, int srcv, int p0, int laneL, int laneR)
{
    #pragma unroll
    for (int n = 0; n < D_STATE; n++) {
        const f32x4 own = *(const f32x4*)(sp_base + n*HW + srcv);
        f32x4 s;
        if (MODE == 0) {
            s = own;
        } else if (MODE == 1) {
            const float nb = __shfl(own.x, laneR, 64);
            s.x = own.y; s.y = own.z; s.z = own.w; s.w = nb;
        } else {
            const float nb = __shfl(own.w, laneL, 64);
            s.x = nb; s.y = own.x; s.z = own.y; s.w = own.z;
        }
        const float anr = an_[n];
        const f32x4 Bn = *(const f32x4*)(Bv_b + n*HW);
        const f32x4 Cn = *(const f32x4*)(Cv_b + n*HW);
        f32x4 ab;
        ab.x = __expf(dl.x * anr);
        ab.y = __expf(dl.y * anr);
        ab.z = __expf(dl.z * anr);
        ab.w = __expf(dl.w * anr);
        const f32x4 sn = ab * s + du * Bn;
        stream_store4(sn_base + n*HW + p0, sn);
        y += sn * Cn;
    }
}

__global__ __launch_bounds__(256) void main_kernel(
    const float* __restrict__ sprev, const float* __restrict__ ut,
    const float* __restrict__ delta, const float* __restrict__ Bv,
    const float* __restrict__ Cv, const float* __restrict__ logA,
    const float* __restrict__ Dp, const int* __restrict__ gidx,
    float* __restrict__ ynew, float* __restrict__ snew)
{
    const int blk = blockIdx.x;
    const int d   = blk % D_MODEL;
    const int tmp = blk / D_MODEL;
    const int v   = tmp % V;
    const int b   = tmp / V;

    const int t  = threadIdx.x;
    const int p0 = t * 4;
    const int y0 = p0 >> 5;
    const int x0 = p0 & 31;

    const int gi0 = gidx[v*HW];       // src index of output point 0
    const int ryo = gi0 >> 5;         // row offset: src_y = (y + ryo) & 31
    const int rxo = gi0 & 31;         // col rotation: src_x = (x + rxo) & 31

    const int ys   = (y0 + ryo) & 31;
    const int srcv = (ys << 5) + x0;  // aligned float4 base in source row

    const int lane  = t & 63;
    const int laneL = (lane & ~7) | ((lane + 7) & 7);
    const int laneR = (lane & ~7) | ((lane + 1) & 7);

    const size_t bvd = (((size_t)b*V + v)*D_MODEL + d);
    const float* sp_base = sprev + bvd * D_STATE * HW;
    float* sn_base = snew + bvd * D_STATE * HW;

    const float dpd = Dp[d];
    float an_[D_STATE];
    #pragma unroll
    for (int n = 0; n < D_STATE; n++) an_[n] = -__expf(logA[d*D_STATE + n]);

    const f32x4 dl = *(const f32x4*)(delta + ((size_t)b*D_MODEL + d)*HW + p0);
    const f32x4 uu = *(const f32x4*)(ut    + ((size_t)b*D_MODEL + d)*HW + p0);
    const f32x4 du = dl * uu;
    const float* Bv_b = Bv + (size_t)b*D_STATE*HW + p0;
    const float* Cv_b = Cv + (size_t)b*D_STATE*HW + p0;

    f32x4 y = uu * dpd;

    if (rxo == 0) {
        main_body<0>(sp_base, sn_base, Bv_b, Cv_b, dl, du, an_, y, srcv, p0, laneL, laneR);
    } else if (rxo == 1) {
        main_body<1>(sp_base, sn_base, Bv_b, Cv_b, dl, du, an_, y, srcv, p0, laneL, laneR);
    } else if (rxo == 31) {
        main_body<2>(sp_base, sn_base, Bv_b, Cv_b, dl, du, an_, y, srcv, p0, laneL, laneR);
    } else {
        // general fallback: scalar gather (not expected for V_RANGE=1)
        const int4 src4 = *(const int4*)(gidx + v*HW + p0);
        #pragma unroll
        for (int n = 0; n < D_STATE; n++) {
            const float* sp_n = sp_base + n*HW;
            const f32x4 Bn = *(const f32x4*)(Bv_b + n*HW);
            const f32x4 Cn = *(const f32x4*)(Cv_b + n*HW);
            const float anr = an_[n];
            f32x4 s;
            s.x = sp_n[src4.x]; s.y = sp_n[src4.y];
            s.z = sp_n[src4.z]; s.w = sp_n[src4.w];
            f32x4 ab;
            ab.x = __expf(dl.x * anr);
            ab.y = __expf(dl.y * anr);
            ab.z = __expf(dl.z * anr);
            ab.w = __expf(dl.w * anr);
            const f32x4 sn = ab * s + du * Bn;
            stream_store4(sn_base + n*HW + p0, sn);
            y += sn * Cn;
        }
    }
    *(f32x4*)(ynew + bvd * HW + p0) = y;
}

extern "C" void kernel_launch(void* const* d_in, const int* in_sizes, int n_in,
                              void* d_out, int out_size, void* d_ws, size_t ws_size,
                              hipStream_t stream)
{
    const float* u_t       = (const float*)d_in[0];
    const float* s_prev    = (const float*)d_in[1];
    const float* gamma     = (const float*)d_in[2];
    const float* beta      = (const float*)d_in[3];
    const float* w_delta   = (const float*)d_in[4];
    const float* b_delta   = (const float*)d_in[5];
    const float* w_B       = (const float*)d_in[6];
    const float* w_C       = (const float*)d_in[7];
    const float* log_A     = (const float*)d_in[8];
    const float* D_param   = (const float*)d_in[9];
    const float* dt_sp     = (const float*)d_in[10];
    const int*   gidx      = (const int*)d_in[11];

    float* ws = (float*)d_ws;
    float* un    = ws;
    float* delta = un    + (size_t)B*D_MODEL*HW;
    float* Bv    = delta + (size_t)B*D_MODEL*HW;
    float* Cv    = Bv    + (size_t)B*D_STATE*HW;

    float* ynew = (float*)d_out;
    float* snew = ynew + (size_t)B*V*D_MODEL*HW;

    gn_kernel<<<B*GROUPS, 256, 0, stream>>>(u_t, gamma, beta, un);
    conv_kernel<<<B*96, 256, 0, stream>>>(un, w_delta, b_delta, w_B, w_C, dt_sp,
                                          delta, Bv, Cv);
    main_kernel<<<B*V*D_MODEL, 256, 0, stream>>>(s_prev, u_t, delta, Bv, Cv,
                                                 log_A, D_param, gidx, ynew, snew);
}

// Round 9
// 102.372 us; speedup vs baseline: 1.0431x; 1.0431x over previous
//
#include <hip/hip_runtime.h>
#include <hip/hip_bf16.h>

#define D_MODEL 64
#define D_STATE 16
#define IMG     32
#define HW      (IMG*IMG)      // 1024
#define V       9
#define B       4
#define GROUPS  4
#define CPG     (D_MODEL/GROUPS) // 16

typedef float f32x4 __attribute__((ext_vector_type(4)));

// ---------------- Kernel 1: GroupNorm ----------------
__global__ __launch_bounds__(256) void gn_kernel(
    const float* __restrict__ u, const float* __restrict__ gamma,
    const float* __restrict__ beta, float* __restrict__ un)
{
    const int b = blockIdx.x / GROUPS;
    const int g = blockIdx.x % GROUPS;
    const float* base = u + ((size_t)b*D_MODEL + g*CPG) * HW;
    const int NE = CPG * HW; // 16384

    float s = 0.f, s2 = 0.f;
    for (int i = threadIdx.x; i < NE; i += 256) {
        float v = base[i];
        s += v; s2 += v*v;
    }
    for (int off = 32; off; off >>= 1) {
        s  += __shfl_down(s,  off);
        s2 += __shfl_down(s2, off);
    }
    __shared__ float red0[4], red1[4];
    const int wave = threadIdx.x >> 6;
    if ((threadIdx.x & 63) == 0) { red0[wave] = s; red1[wave] = s2; }
    __syncthreads();
    if (threadIdx.x == 0) {
        float a = 0.f, c = 0.f;
        for (int i = 0; i < 4; i++) { a += red0[i]; c += red1[i]; }
        red0[0] = a; red1[0] = c;
    }
    __syncthreads();
    const float mean = red0[0] * (1.f/16384.f);
    const float var  = red1[0] * (1.f/16384.f) - mean*mean;
    const float rstd = rsqrtf(var + 1e-5f);

    for (int i = threadIdx.x; i < NE; i += 256) {
        int c = i >> 10;
        int d = g*CPG + c;
        float v = (base[i] - mean) * rstd;
        un[((size_t)b*D_MODEL + d)*HW + (i & (HW-1))] = v*gamma[d] + beta[d];
    }
}

// ---------------- Kernel 2: circular 3x3 convs, LDS-staged, 4 co / block ----------------
__global__ __launch_bounds__(256) void conv_kernel(
    const float* __restrict__ un,
    const float* __restrict__ w_delta, const float* __restrict__ b_delta,
    const float* __restrict__ w_B, const float* __restrict__ w_C,
    const float* __restrict__ dt_sp,
    float* __restrict__ delta, float* __restrict__ Bv, float* __restrict__ Cv)
{
    const int bx    = blockIdx.x;
    const int strip = bx & 3;
    const int cog   = (bx >> 2) % 24;
    const int b     = bx / 96;
    const int co0   = cog * 4;
    const int row0  = strip * 8;

    __shared__ float xs[16][10][32];
    __shared__ float wl[4][D_MODEL*9];

    for (int i = threadIdx.x; i < 4*D_MODEL*9; i += 256) {
        const int cl = i / (D_MODEL*9);
        const int rest = i % (D_MODEL*9);
        const int co = co0 + cl;
        const float* w = (co < 64) ? (w_delta + (size_t)co*(D_MODEL*9))
                       : (co < 80) ? (w_B + (size_t)(co-64)*(D_MODEL*9))
                                   : (w_C + (size_t)(co-80)*(D_MODEL*9));
        wl[cl][rest] = w[rest];
    }

    const int ly = threadIdx.x >> 5;
    const int ox = threadIdx.x & 31;
    const int oy = row0 + ly;

    const float* x = un + (size_t)b*D_MODEL*HW;
    float a0 = 0.f, a1 = 0.f, a2 = 0.f, a3 = 0.f;

    for (int c = 0; c < 4; c++) {
        __syncthreads();
        for (int i = threadIdx.x; i < 16*10*32; i += 256) {
            const int ci = i / 320;
            const int rr = (i % 320) >> 5;
            const int xx = i & 31;
            const int gy = (row0 - 1 + rr) & 31;
            xs[ci][rr][xx] = x[(size_t)(c*16 + ci)*HW + (gy << 5) + xx];
        }
        __syncthreads();

        #pragma unroll
        for (int ci = 0; ci < 16; ci++) {
            float v[3][3];
            #pragma unroll
            for (int dy = 0; dy < 3; dy++)
                #pragma unroll
                for (int dx = 0; dx < 3; dx++)
                    v[dy][dx] = xs[ci][ly + dy][(ox + dx + 31) & 31];
            const int cig = c*16 + ci;
            const float* w0 = &wl[0][cig*9];
            const float* w1 = &wl[1][cig*9];
            const float* w2 = &wl[2][cig*9];
            const float* w3 = &wl[3][cig*9];
            #pragma unroll
            for (int t = 0; t < 9; t++) {
                const float xv = v[t/3][t%3];
                a0 = fmaf(xv, w0[t], a0);
                a1 = fmaf(xv, w1[t], a1);
                a2 = fmaf(xv, w2[t], a2);
                a3 = fmaf(xv, w3[t], a3);
            }
        }
    }

    const int p = (oy << 5) + ox;
    const float dtsp = dt_sp[0];
    float accs[4] = {a0, a1, a2, a3};
    #pragma unroll
    for (int cl = 0; cl < 4; cl++) {
        const int co = co0 + cl;
        float acc = accs[cl];
        if (co < 64) {
            acc += b_delta[co] + dtsp;
            float sp = (acc > 15.f) ? acc : log1pf(__expf(acc));
            sp = fminf(fmaxf(sp, 1e-4f), 5.f);
            delta[((size_t)b*D_MODEL + co)*HW + p] = sp;
        } else if (co < 80) {
            Bv[((size_t)b*D_STATE + (co-64))*HW + p] = acc;
        } else {
            Cv[((size_t)b*D_STATE + (co-80))*HW + p] = acc;
        }
    }
}

// ---------------- Kernel 3: main fused state update (asm-pipelined) ----------------
// grid = B*V*D_MODEL (2304) blocks x 256 threads.
// All loop VMEM as inline-asm global_load_dwordx4 (SGPR base + 32-bit voffset),
// uniform prefetch depth 4 planes across the 3 read streams, fully unrolled
// 16 iterations with exact counted s_waitcnt vmcnt(K) (stores accounted in the
// in-order counter), sched_barrier(0) after each wait. Stores: nt.
__device__ __forceinline__ f32x4 asm_load4(const float* __restrict__ base, unsigned voff) {
    f32x4 d;
    asm volatile("global_load_dwordx4 %0, %1, %2"
                 : "=v"(d) : "v"(voff), "s"(base) : "memory");
    return d;
}

// K(n) = 3*(min(n+4,15)-n) newer loads + min(4,n) newer stores
#define STEP(n, K) do { \
    if ((n) + 4 <= 15) { \
        sp[((n)+4)&15] = asm_load4(sp_u, sp_voff + ((n)+4)*4096u); \
        Bn[((n)+4)&15] = asm_load4(Bv_u, bc_voff + ((n)+4)*4096u); \
        Cn[((n)+4)&15] = asm_load4(Cv_u, bc_voff + ((n)+4)*4096u); \
    } \
    asm volatile("s_waitcnt vmcnt(" #K ")" ::: "memory"); \
    __builtin_amdgcn_sched_barrier(0); \
    { \
        const f32x4 own = sp[(n)]; \
        f32x4 s; \
        if (MODE == 0) { s = own; } \
        else if (MODE == 1) { const float nb = __shfl(own.x, laneR, 64); \
                              s.x = own.y; s.y = own.z; s.z = own.w; s.w = nb; } \
        else { const float nb = __shfl(own.w, laneL, 64); \
               s.x = nb; s.y = own.x; s.z = own.y; s.w = own.z; } \
        const float anr = an_[(n)]; \
        f32x4 ab; \
        ab.x = __expf(dl.x*anr); ab.y = __expf(dl.y*anr); \
        ab.z = __expf(dl.z*anr); ab.w = __expf(dl.w*anr); \
        const f32x4 snv = ab*s + du*Bn[(n)]; \
        __builtin_nontemporal_store(snv, (f32x4*)(sn_p + (n)*HW)); \
        y += snv * Cn[(n)]; \
    } \
} while (0)

template<int MODE>
__device__ __forceinline__ void pipe_body(
    const float* __restrict__ sp_u, unsigned sp_voff,
    const float* __restrict__ Bv_u, const float* __restrict__ Cv_u, unsigned bc_voff,
    float* __restrict__ sn_p,
    const f32x4 dl, const f32x4 du, const float* an_,
    f32x4& y, int laneL, int laneR)
{
    f32x4 sp[16], Bn[16], Cn[16];
    #pragma unroll
    for (int p = 0; p < 4; p++) {
        sp[p] = asm_load4(sp_u, sp_voff + p*4096u);
        Bn[p] = asm_load4(Bv_u, bc_voff + p*4096u);
        Cn[p] = asm_load4(Cv_u, bc_voff + p*4096u);
    }
    STEP(0, 12); STEP(1, 13); STEP(2, 14); STEP(3, 15);
    STEP(4, 16); STEP(5, 16); STEP(6, 16); STEP(7, 16);
    STEP(8, 16); STEP(9, 16); STEP(10, 16); STEP(11, 16);
    STEP(12, 13); STEP(13, 10); STEP(14, 7); STEP(15, 4);
}

__global__ __launch_bounds__(256) void main_kernel(
    const float* __restrict__ sprev, const float* __restrict__ ut,
    const float* __restrict__ delta, const float* __restrict__ Bv,
    const float* __restrict__ Cv, const float* __restrict__ logA,
    const float* __restrict__ Dp, const int* __restrict__ gidx,
    float* __restrict__ ynew, float* __restrict__ snew)
{
    const int blk = blockIdx.x;
    const int d   = blk % D_MODEL;
    const int tmp = blk / D_MODEL;
    const int v   = tmp % V;
    const int b   = tmp / V;

    const int t  = threadIdx.x;
    const int p0 = t * 4;
    const int y0 = p0 >> 5;
    const int x0 = p0 & 31;

    const int gi0 = gidx[v*HW];       // src index of output point 0
    const int ryo = gi0 >> 5;         // row offset: src_y = (y + ryo) & 31
    const int rxo = gi0 & 31;         // col rotation: src_x = (x + rxo) & 31

    const int ys   = (y0 + ryo) & 31;
    const int srcv = (ys << 5) + x0;  // aligned float4 base in source row

    const int lane  = t & 63;
    const int laneL = (lane & ~7) | ((lane + 7) & 7);
    const int laneR = (lane & ~7) | ((lane + 1) & 7);

    const size_t bvd = (((size_t)b*V + v)*D_MODEL + d);
    const float* sp_u = sprev + bvd * D_STATE * HW;   // uniform base
    float* sn_p = snew + bvd * D_STATE * HW + p0;

    const float dpd = Dp[d];
    float an_[D_STATE];
    #pragma unroll
    for (int n = 0; n < D_STATE; n++) an_[n] = -__expf(logA[d*D_STATE + n]);

    const f32x4 dl = *(const f32x4*)(delta + ((size_t)b*D_MODEL + d)*HW + p0);
    const f32x4 uu = *(const f32x4*)(ut    + ((size_t)b*D_MODEL + d)*HW + p0);
    const f32x4 du = dl * uu;
    const float* Bv_u = Bv + (size_t)b*D_STATE*HW;    // uniform base
    const float* Cv_u = Cv + (size_t)b*D_STATE*HW;    // uniform base

    f32x4 y = uu * dpd;

    const unsigned sp_voff = (unsigned)srcv * 4u;
    const unsigned bc_voff = (unsigned)p0 * 4u;

    if (rxo == 0) {
        pipe_body<0>(sp_u, sp_voff, Bv_u, Cv_u, bc_voff, sn_p, dl, du, an_, y, laneL, laneR);
    } else if (rxo == 1) {
        pipe_body<1>(sp_u, sp_voff, Bv_u, Cv_u, bc_voff, sn_p, dl, du, an_, y, laneL, laneR);
    } else if (rxo == 31) {
        pipe_body<2>(sp_u, sp_voff, Bv_u, Cv_u, bc_voff, sn_p, dl, du, an_, y, laneL, laneR);
    } else {
        // general fallback: scalar gather (not expected for V_RANGE=1)
        const int4 src4 = *(const int4*)(gidx + v*HW + p0);
        #pragma unroll
        for (int n = 0; n < D_STATE; n++) {
            const float* sp_n = sp_u + n*HW;
            const f32x4 Bn = *(const f32x4*)(Bv_u + n*HW + p0);
            const f32x4 Cn = *(const f32x4*)(Cv_u + n*HW + p0);
            const float anr = an_[n];
            f32x4 s;
            s.x = sp_n[src4.x]; s.y = sp_n[src4.y];
            s.z = sp_n[src4.z]; s.w = sp_n[src4.w];
            f32x4 ab;
            ab.x = __expf(dl.x * anr);
            ab.y = __expf(dl.y * anr);
            ab.z = __expf(dl.z * anr);
            ab.w = __expf(dl.w * anr);
            const f32x4 sn = ab * s + du * Bn;
            __builtin_nontemporal_store(sn, (f32x4*)(sn_p + n*HW));
            y += sn * Cn;
        }
    }
    *(f32x4*)(ynew + bvd * HW + p0) = y;
}

extern "C" void kernel_launch(void* const* d_in, const int* in_sizes, int n_in,
                              void* d_out, int out_size, void* d_ws, size_t ws_size,
                              hipStream_t stream)
{
    const float* u_t       = (const float*)d_in[0];
    const float* s_prev    = (const float*)d_in[1];
    const float* gamma     = (const float*)d_in[2];
    const float* beta      = (const float*)d_in[3];
    const float* w_delta   = (const float*)d_in[4];
    const float* b_delta   = (const float*)d_in[5];
    const float* w_B       = (const float*)d_in[6];
    const float* w_C       = (const float*)d_in[7];
    const float* log_A     = (const float*)d_in[8];
    const float* D_param   = (const float*)d_in[9];
    const float* dt_sp     = (const float*)d_in[10];
    const int*   gidx      = (const int*)d_in[11];

    float* ws = (float*)d_ws;
    float* un    = ws;
    float* delta = un    + (size_t)B*D_MODEL*HW;
    float* Bv    = delta + (size_t)B*D_MODEL*HW;
    float* Cv    = Bv    + (size_t)B*D_STATE*HW;

    float* ynew = (float*)d_out;
    float* snew = ynew + (size_t)B*V*D_MODEL*HW;

    gn_kernel<<<B*GROUPS, 256, 0, stream>>>(u_t, gamma, beta, un);
    conv_kernel<<<B*96, 256, 0, stream>>>(un, w_delta, b_delta, w_B, w_C, dt_sp,
                                          delta, Bv, Cv);
    main_kernel<<<B*V*D_MODEL, 256, 0, stream>>>(s_prev, u_t, delta, Bv, Cv,
                                                 log_A, D_param, gidx, ynew, snew);
}